// Round 8
// baseline (344.468 us; speedup 1.0000x reference)
//
#include <hip/hip_runtime.h>
#include <math.h>

// ---------------------------------------------------------------------------
// R7 = R5 resubmit x2 (R5, R6 both hit GPUAcquisitionTimeout; never ran).
// R4 (validated 8-phase 256^2 gemm8, bank-conflicts measured 0) plus:
//   * PV split-K2: grid z=8 -> (batch = z>>1, chunk = z&1), 256 blocks (was
//     128 = half-chip). Epilogue atomicAdd f32 into zeroed ctx; exactly 2
//     commutative adds per element -> bitwise deterministic.
//   * zerofill kernel for ctx (graph-capture-safe, no memset dependency).
//   * softmax uses __expf (hw v_exp path).
//   * 3 weight-cast launches fused into one (contiguous Wqk|Wv dst).
// Unchanged: QK-proj (256 blocks), Vt-proj (128 blocks - known half-chip,
// fix candidate next round), scores (256 blocks), schedule/swizzle/vmcnt.
// Predicted: PV 61->~33us, MfmaUtil(PV) ~40%, total ~265-280us.
// ---------------------------------------------------------------------------

typedef __bf16 bf16;
typedef __bf16 bf16x4 __attribute__((ext_vector_type(4)));
typedef __bf16 bf16x8 __attribute__((ext_vector_type(8)));
typedef float  f32x4  __attribute__((ext_vector_type(4)));

#define GLD_TO_LDS(g, l) __builtin_amdgcn_global_load_lds(                    \
    (const __attribute__((address_space(1))) void*)(g),                       \
    (__attribute__((address_space(3))) void*)(l), 16, 0, 0)

#define STAGE_A(tc, P, h) do {                                                \
    const bf16* _s = aRow + (long)((h) * 128) * lda + (long)(tc) * 64;        \
    char* _d = ldsA + (P) * 32768 + (h) * 16384 + t * 16;                     \
    GLD_TO_LDS(_s, _d); GLD_TO_LDS(_s + 64L * lda, _d + 8192); } while (0)
#define STAGE_B(tc, P, h) do {                                                \
    const bf16* _s = bRow + (long)((h) * 128) * ldb + (long)(tc) * 64;        \
    char* _d = ldsB + (P) * 32768 + (h) * 16384 + t * 16;                     \
    GLD_TO_LDS(_s, _d); GLD_TO_LDS(_s + 64L * ldb, _d + 8192); } while (0)
#define VMCNT4 asm volatile("s_waitcnt vmcnt(4)" ::: "memory")

// C[M,N] = alpha * A[M,K] * B[N,K]^T ; bf16 in, f32 acc.
// OUT: 0=f32 store, 1=bf16 store, 2=f32 atomicAdd (split-K accumulate).
// SPLITK: blockIdx.z = (batch<<1)|chunk; chunk offsets A,B by sKa,sKb elems.
template<int OUT, bool SPLITK>
__global__ __launch_bounds__(512, 2)
void gemm8(const bf16* __restrict__ A, const bf16* __restrict__ B,
           void* __restrict__ Cp, int nkt, int lda, int ldb, int ldc,
           long sA, long sB, long sC, long sKa, long sKb, float alpha)
{
    __shared__ __align__(16) char smem[131072];
    char* ldsA = smem;            // [2][256][64] bf16 (swizzled slots)
    char* ldsB = smem + 65536;

    const int bz = SPLITK ? (blockIdx.z >> 1) : blockIdx.z;
    A += bz * sA;
    B += bz * sB;
    if (SPLITK) {
        const int ck = blockIdx.z & 1;
        A += ck * sKa;
        B += ck * sKb;
    }

    const int t    = threadIdx.x;
    const int wid  = t >> 6;
    const int lane = t & 63;
    const int wr   = wid >> 2;          // 0..1 : wave M-block (128 rows)
    const int wn   = wid & 3;           // 0..3 : wave N-block (64 cols)
    const int fr   = lane & 15;         // frag row (A) / col-row (B)
    const int g    = lane >> 4;         // 0..3
    const int brow = blockIdx.y * 256;
    const int bcol = blockIdx.x * 256;

    // staging source (pre-swizzled global col so linear LDS holds swz layout)
    const int  srow = t >> 3;                              // 0..63
    const int  scol = ((t & 7) ^ ((t >> 3) & 7)) * 8;      // elements
    const bf16* aRow = A + (long)(brow + srow) * lda + scol;
    const bf16* bRow = B + (long)(bcol + srow) * ldb + scol;

    // ds_read bases; col = (ks*64 + g*16) ^ ((fr&7)<<4)
    const int  c0  = (g * 16) ^ ((fr & 7) << 4);
    const int  c1  = c0 ^ 64;
    const char* aRd = ldsA + (wr * 128 + fr) * 128;
    const char* bRd = ldsB + (wn * 64 + fr) * 128;

    f32x4 acc[8][4] = {};
    bf16x8 bfrag[4][2];

    // prologue: stage tiles 0,1 fully (16 loads), drain tile 0
    STAGE_A(0, 0, 0); STAGE_A(0, 0, 1); STAGE_B(0, 0, 0); STAGE_B(0, 0, 1);
    STAGE_A(1, 1, 0); STAGE_A(1, 1, 1); STAGE_B(1, 1, 0); STAGE_B(1, 1, 1);
    asm volatile("s_waitcnt vmcnt(8)" ::: "memory");
    __builtin_amdgcn_s_barrier();

    const int niter = nkt >> 1;
    for (int it = 0; it < niter; ++it) {
        const int cur = 2 * it;
        const int tc2 = (cur + 2 < nkt) ? cur + 2 : nkt - 1;
        const int tc3 = (cur + 3 < nkt) ? cur + 3 : nkt - 1;
        #pragma unroll
        for (int ph = 0; ph < 8; ++ph) {
            const int q = ph & 3;       // quadrant (2 M-frags)
            const int P = ph >> 2;      // tile parity / LDS slot

            if (q == 0) {               // B-frags once per K-tile (8 reads)
                #pragma unroll
                for (int n = 0; n < 4; ++n) {
                    bfrag[n][0] = *reinterpret_cast<const bf16x8*>(
                        bRd + P * 32768 + n * 2048 + c0);
                    bfrag[n][1] = *reinterpret_cast<const bf16x8*>(
                        bRd + P * 32768 + n * 2048 + c1);
                }
            }
            bf16x8 af[2][2];            // A-frags for this quadrant (4 reads)
            #pragma unroll
            for (int i = 0; i < 2; ++i) {
                af[i][0] = *reinterpret_cast<const bf16x8*>(
                    aRd + P * 32768 + (2 * q + i) * 2048 + c0);
                af[i][1] = *reinterpret_cast<const bf16x8*>(
                    aRd + P * 32768 + (2 * q + i) * 2048 + c1);
            }

            // staging schedule (slot-death-safe, uniform counts)
            if (ph == 0) STAGE_A(cur + 1, 1, 0);
            if (ph == 1) STAGE_A(cur + 1, 1, 1);
            if (ph == 2) STAGE_B(tc2, 0, 0);
            if (ph == 3) { STAGE_B(tc2, 0, 1); VMCNT4; }
            if (ph == 4) STAGE_A(tc2, 0, 0);
            if (ph == 5) STAGE_A(tc2, 0, 1);
            if (ph == 6) STAGE_B(tc3, 1, 0);
            if (ph == 7) { STAGE_B(tc3, 1, 1); VMCNT4; }

            __builtin_amdgcn_s_barrier();
            __builtin_amdgcn_s_setprio(1);
            #pragma unroll
            for (int i = 0; i < 2; ++i)
                #pragma unroll
                for (int n = 0; n < 4; ++n) {
                    acc[2 * q + i][n] = __builtin_amdgcn_mfma_f32_16x16x32_bf16(
                        af[i][0], bfrag[n][0], acc[2 * q + i][n], 0, 0, 0);
                    acc[2 * q + i][n] = __builtin_amdgcn_mfma_f32_16x16x32_bf16(
                        af[i][1], bfrag[n][1], acc[2 * q + i][n], 0, 0, 0);
                }
            __builtin_amdgcn_s_setprio(0);
            __builtin_amdgcn_s_barrier();
        }
    }

    // epilogue: C/D layout col = lane&15, row = (lane>>4)*4 + rr (m89-verified)
    #pragma unroll
    for (int m = 0; m < 8; ++m) {
        #pragma unroll
        for (int n = 0; n < 4; ++n) {
            const int ccol = bcol + wn * 64 + n * 16 + fr;
            #pragma unroll
            for (int rr = 0; rr < 4; ++rr) {
                const long crow = brow + wr * 128 + m * 16 + g * 4 + rr;
                const float v = acc[m][n][rr] * alpha;
                if constexpr (OUT == 0) {
                    ((float*)Cp + bz * sC)[crow * ldc + ccol] = v;
                } else if constexpr (OUT == 1) {
                    ((bf16*)Cp + bz * sC)[crow * ldc + ccol] = (bf16)v;
                } else {
                    atomicAdd(&((float*)Cp + bz * sC)[crow * ldc + ccol], v);
                }
            }
        }
    }
}

// fp32 -> bf16 cast, vectorized x4, grid-stride.
__global__ __launch_bounds__(256)
void cast_bf16(const float* __restrict__ in, bf16* __restrict__ out, int n4)
{
    int i = blockIdx.x * 256 + threadIdx.x;
    const int stride = gridDim.x * 256;
    for (; i < n4; i += stride) {
        float4 v = reinterpret_cast<const float4*>(in)[i];
        bf16x4 o = { (bf16)v.x, (bf16)v.y, (bf16)v.z, (bf16)v.w };
        reinterpret_cast<bf16x4*>(out)[i] = o;
    }
}

// fused Wq|Wk|Wv cast into contiguous [3072,1024] bf16 dst (Wqk then Wv).
// grid exactly 3072 blocks x 256 threads, one float4 per thread.
__global__ __launch_bounds__(256)
void cast_w3(const float* __restrict__ Wq, const float* __restrict__ Wk,
             const float* __restrict__ Wv, bf16* __restrict__ dst)
{
    const int idx = blockIdx.x * 256 + threadIdx.x;     // 0 .. 786431
    const float* src;
    int off;
    if (idx < 262144)      { src = Wq; off = idx; }
    else if (idx < 524288) { src = Wk; off = idx - 262144; }
    else                   { src = Wv; off = idx - 524288; }
    float4 v = reinterpret_cast<const float4*>(src)[off];
    bf16x4 o = { (bf16)v.x, (bf16)v.y, (bf16)v.z, (bf16)v.w };
    reinterpret_cast<bf16x4*>(dst)[idx] = o;
}

// zero-fill (for split-K atomic accumulate target)
__global__ __launch_bounds__(256)
void zerofill(float4* __restrict__ p, int n4)
{
    const int i = blockIdx.x * 256 + threadIdx.x;
    if (i < n4) p[i] = float4{0.f, 0.f, 0.f, 0.f};
}

// In-place row softmax (f32) + bf16 copy; one block per row of 2048.
__global__ __launch_bounds__(256)
void softmax_rows(float* __restrict__ W, bf16* __restrict__ Wb)
{
    float* p  = W  + (long)blockIdx.x * 2048;
    bf16*  pb = Wb + (long)blockIdx.x * 2048;
    const int tid  = threadIdx.x;
    const int wid  = tid >> 6;
    const int lane = tid & 63;

    float4 v0 = reinterpret_cast<const float4*>(p)[tid];
    float4 v1 = reinterpret_cast<const float4*>(p)[tid + 256];

    float m = fmaxf(fmaxf(fmaxf(v0.x, v0.y), fmaxf(v0.z, v0.w)),
                    fmaxf(fmaxf(v1.x, v1.y), fmaxf(v1.z, v1.w)));
    #pragma unroll
    for (int off = 32; off >= 1; off >>= 1)
        m = fmaxf(m, __shfl_xor(m, off));

    __shared__ float red[8];
    if (lane == 0) red[wid] = m;
    __syncthreads();
    m = fmaxf(fmaxf(red[0], red[1]), fmaxf(red[2], red[3]));

    v0.x = __expf(v0.x - m); v0.y = __expf(v0.y - m);
    v0.z = __expf(v0.z - m); v0.w = __expf(v0.w - m);
    v1.x = __expf(v1.x - m); v1.y = __expf(v1.y - m);
    v1.z = __expf(v1.z - m); v1.w = __expf(v1.w - m);

    float s = (v0.x + v0.y + v0.z + v0.w) + (v1.x + v1.y + v1.z + v1.w);
    #pragma unroll
    for (int off = 32; off >= 1; off >>= 1)
        s += __shfl_xor(s, off);
    __syncthreads();
    if (lane == 0) red[4 + wid] = s;
    __syncthreads();
    s = (red[4] + red[5]) + (red[6] + red[7]);

    const float inv = 1.f / s;
    v0.x *= inv; v0.y *= inv; v0.z *= inv; v0.w *= inv;
    v1.x *= inv; v1.y *= inv; v1.z *= inv; v1.w *= inv;
    reinterpret_cast<float4*>(p)[tid]       = v0;
    reinterpret_cast<float4*>(p)[tid + 256] = v1;
    bf16x4 b0 = { (bf16)v0.x, (bf16)v0.y, (bf16)v0.z, (bf16)v0.w };
    bf16x4 b1 = { (bf16)v1.x, (bf16)v1.y, (bf16)v1.z, (bf16)v1.w };
    reinterpret_cast<bf16x4*>(pb)[tid]       = b0;
    reinterpret_cast<bf16x4*>(pb)[tid + 256] = b1;
}

extern "C" void kernel_launch(void* const* d_in, const int* in_sizes, int n_in,
                              void* d_out, int out_size, void* d_ws, size_t ws_size,
                              hipStream_t stream)
{
    const float* X  = (const float*)d_in[0];   // [4,2048,1024]
    const float* Wq = (const float*)d_in[1];   // [1024,1024]
    const float* Wk = (const float*)d_in[2];
    const float* Wv = (const float*)d_in[3];

    const long BT = 4L * 2048;                 // 8192 total rows
    const long D  = 1024;
    const long S  = 2048;
    const long MiB = 1024 * 1024;

    float* ctx = (float*)d_out;                // [4,2048,1024]
    float* wts = (float*)d_out + BT * D;       // [4,2048,2048]

    char* ws   = (char*)d_ws;
    bf16* Xb   = (bf16*)(ws);                  // 16 MiB [0,16)
    bf16* Wqkb = (bf16*)(ws + 16 * MiB);       //  4 MiB [16,20)  [2048,1024]
    // Wvb at [20,22) is Wqkb + 2*D*D (contiguous, written by cast_w3)
    bf16* Wvb  = (bf16*)(ws + 20 * MiB);
    bf16* QKb  = (bf16*)(ws + 22 * MiB);       // 32 MiB [22,54)  [8192,2048]
    bf16* Vtb  = (bf16*)(ws + 54 * MiB);       // 16 MiB [54,70)  [1024,8192]
    bf16* Wbf  = (bf16*)(ws);                  // 32 MiB, aliases dead [0,32)

    dim3 blk(256), blk8(512);

    // casts: X -> Xb ; Wq|Wk|Wv -> [Wqkb|Wvb] contiguous
    cast_bf16<<<dim3(2048), blk, 0, stream>>>(X, Xb, (int)(BT * D / 4));
    cast_w3<<<dim3(3072), blk, 0, stream>>>(Wq, Wk, Wv, Wqkb);
    // zero ctx for split-K atomic accumulate
    zerofill<<<dim3(8192), blk, 0, stream>>>((float4*)ctx, (int)(BT * D / 4));

    // fused QK projection: QKb[8192,2048] = NT(Xb, Wqkb)
    gemm8<1, false><<<dim3(8, 32, 1), blk8, 0, stream>>>(
        Xb, Wqkb, QKb, 16, 1024, 1024, 2048, 0, 0, 0, 0, 0, 1.f);
    // Vt projection: Vtb[1024,8192] = NT(Wvb, Xb)
    gemm8<1, false><<<dim3(32, 4, 1), blk8, 0, stream>>>(
        Wvb, Xb, Vtb, 16, 1024, 1024, 8192, 0, 0, 0, 0, 0, 1.f);
    // scores: S_b = NT(Q_b, K_b) / 32 -> f32 weights region
    gemm8<0, false><<<dim3(8, 8, 4), blk8, 0, stream>>>(
        QKb, QKb + 1024, wts, 16, 2048, 2048, 2048,
        S * 2048, S * 2048, S * S, 0, 0, 0.03125f);
    // softmax rows (f32 in place) + bf16 copy
    softmax_rows<<<dim3(BT), blk, 0, stream>>>(wts, Wbf);

    // context (split-K2): z = (batch<<1)|chunk, 256 blocks, atomicAdd accum.
    // chunk offsets: A cols += 1024 (lda 2048), B cols += 1024 (ldb 8192).
    gemm8<2, true><<<dim3(4, 8, 8), blk8, 0, stream>>>(
        Wbf, Vtb, ctx, 16, 2048, 8192, 1024,
        S * S, S, S * D, 1024, 1024, 1.f);
}

// Round 10
// 290.626 us; speedup vs baseline: 1.1853x; 1.1853x over previous
//
#include <hip/hip_runtime.h>
#include <math.h>

// ---------------------------------------------------------------------------
// R9 = R8 resubmit (R8 hit "container failed twice" infra error; never ran).
// R8: revert R7's atomic split-K (measured: PV 61->83us, atomics RMW cost >
// chip-fill gain). Fix for half-chip dispatches: BN=128 tile variant
// (256Mx128N) of the SAME validated 8-phase schedule -> 256 blocks with
// plain stores, zero extra traffic, deterministic.
//   gemm8<OUT,BN>: BN=256 (validated R4 path, byte-identical) or BN=128:
//     B-tile [128][64], B-stage = 1 gload (64 rows), NB=2 b-frags,
//     acc[8][2], wave col base wn*32, LDS 96KB.
//     vmcnt re-derived (FIFO): steady vmcnt(2) at ph3/ph7, prologue vmcnt(6).
//     Slot-death unchanged: B slot read only at ph0/ph4, staged ph2/ph6 (+2
//     barriers later); A slot last read ph3/ph7, staged ph4/ph0 (+1 barrier).
// Launches: QK-proj BN=256 (8,32) | Vt-proj BN=128 (64,4)=256 blk |
//           scores BN=256 (8,8,4) | PV BN=128 (8,8,4)=256 blk, K=2048.
// Predicted: PV ~37us, Vt ~19us, no 64MB-write dispatch, total ~270-285us.
// ---------------------------------------------------------------------------

typedef __bf16 bf16;
typedef __bf16 bf16x4 __attribute__((ext_vector_type(4)));
typedef __bf16 bf16x8 __attribute__((ext_vector_type(8)));
typedef float  f32x4  __attribute__((ext_vector_type(4)));

#define GLD_TO_LDS(g, l) __builtin_amdgcn_global_load_lds(                    \
    (const __attribute__((address_space(1))) void*)(g),                       \
    (__attribute__((address_space(3))) void*)(l), 16, 0, 0)

// A half-tile: 128 rows, 2 gloads (8KB each). Same for both BN.
#define STAGE_A(tc, P, h) do {                                                \
    const bf16* _s = aRow + (long)((h) * 128) * lda + (long)(tc) * 64;        \
    char* _d = ldsA + (P) * 32768 + (h) * 16384 + t * 16;                     \
    GLD_TO_LDS(_s, _d); GLD_TO_LDS(_s + 64L * lda, _d + 8192); } while (0)
// B half-tile: BN/2 rows. BN=256: 2 gloads (matches R4 exactly); BN=128: 1.
#define STAGE_B(tc, P, h) do {                                                \
    const bf16* _s = bRow + (long)((h) * (BN / 2)) * ldb + (long)(tc) * 64;   \
    char* _d = ldsB + (P) * (BN * 128) + (h) * (BN * 64) + t * 16;            \
    GLD_TO_LDS(_s, _d);                                                       \
    if constexpr (BN == 256) GLD_TO_LDS(_s + 64L * ldb, _d + 8192); } while (0)
// steady-state counted wait: 2 B-stage loads allowed outstanding
#define VMCNT_S do {                                                          \
    if constexpr (BN == 256) asm volatile("s_waitcnt vmcnt(4)" ::: "memory"); \
    else                     asm volatile("s_waitcnt vmcnt(2)" ::: "memory"); \
    } while (0)

// C[M,N] = alpha * A[M,K] * B[N,K]^T ; bf16 in, f32 acc. Row-major.
// OUT: 0=f32 store, 1=bf16 store. Tile 256 x BN. Batched via blockIdx.z.
// Requires M%256==0, N%BN==0, nkt even >= 2.
template<int OUT, int BN>
__global__ __launch_bounds__(512, 2)
void gemm8(const bf16* __restrict__ A, const bf16* __restrict__ B,
           void* __restrict__ Cp, int nkt, int lda, int ldb, int ldc,
           long sA, long sB, long sC, float alpha)
{
    constexpr int NB = BN / 64;             // b-frags per wave (4 or 2)
    __shared__ __align__(16) char smem[65536 + BN * 256];
    char* ldsA = smem;                      // [2][256][64] bf16 (swz slots)
    char* ldsB = smem + 65536;              // [2][BN][64]

    const int bz = blockIdx.z;
    A += bz * sA;
    B += bz * sB;

    const int t    = threadIdx.x;
    const int wid  = t >> 6;
    const int lane = t & 63;
    const int wr   = wid >> 2;          // 0..1 : wave M-block (128 rows)
    const int wn   = wid & 3;           // 0..3 : wave N-block (BN/4 cols)
    const int fr   = lane & 15;         // frag row (A) / col-row (B)
    const int g    = lane >> 4;         // 0..3
    const int brow = blockIdx.y * 256;
    const int bcol = blockIdx.x * BN;

    // staging source (pre-swizzled global col so linear LDS holds swz layout)
    const int  srow = t >> 3;                              // 0..63
    const int  scol = ((t & 7) ^ ((t >> 3) & 7)) * 8;      // elements
    const bf16* aRow = A + (long)(brow + srow) * lda + scol;
    const bf16* bRow = B + (long)(bcol + srow) * ldb + scol;

    // ds_read bases; col byte = (g*16) ^ ((fr&7)<<4), second k-half ^64
    const int  c0  = (g * 16) ^ ((fr & 7) << 4);
    const int  c1  = c0 ^ 64;
    const char* aRd = ldsA + (wr * 128 + fr) * 128;
    const char* bRd = ldsB + (wn * (BN / 4) + fr) * 128;

    f32x4 acc[8][NB] = {};
    bf16x8 bfrag[NB][2];

    // prologue: stage tiles 0,1 fully, drain tile 0 (keep tile 1 in flight)
    STAGE_A(0, 0, 0); STAGE_A(0, 0, 1); STAGE_B(0, 0, 0); STAGE_B(0, 0, 1);
    STAGE_A(1, 1, 0); STAGE_A(1, 1, 1); STAGE_B(1, 1, 0); STAGE_B(1, 1, 1);
    if constexpr (BN == 256) asm volatile("s_waitcnt vmcnt(8)" ::: "memory");
    else                     asm volatile("s_waitcnt vmcnt(6)" ::: "memory");
    __builtin_amdgcn_s_barrier();

    const int niter = nkt >> 1;
    for (int it = 0; it < niter; ++it) {
        const int cur = 2 * it;
        const int tc2 = (cur + 2 < nkt) ? cur + 2 : nkt - 1;
        const int tc3 = (cur + 3 < nkt) ? cur + 3 : nkt - 1;
        #pragma unroll
        for (int ph = 0; ph < 8; ++ph) {
            const int q = ph & 3;       // quadrant (2 M-frags)
            const int P = ph >> 2;      // tile parity / LDS slot

            if (q == 0) {               // B-frags once per K-tile
                #pragma unroll
                for (int n = 0; n < NB; ++n) {
                    bfrag[n][0] = *reinterpret_cast<const bf16x8*>(
                        bRd + P * (BN * 128) + n * 2048 + c0);
                    bfrag[n][1] = *reinterpret_cast<const bf16x8*>(
                        bRd + P * (BN * 128) + n * 2048 + c1);
                }
            }
            bf16x8 af[2][2];            // A-frags for this quadrant
            #pragma unroll
            for (int i = 0; i < 2; ++i) {
                af[i][0] = *reinterpret_cast<const bf16x8*>(
                    aRd + P * 32768 + (2 * q + i) * 2048 + c0);
                af[i][1] = *reinterpret_cast<const bf16x8*>(
                    aRd + P * 32768 + (2 * q + i) * 2048 + c1);
            }

            // staging schedule (slot-death-safe, counted waits)
            if (ph == 0) STAGE_A(cur + 1, 1, 0);
            if (ph == 1) STAGE_A(cur + 1, 1, 1);
            if (ph == 2) STAGE_B(tc2, 0, 0);
            if (ph == 3) { STAGE_B(tc2, 0, 1); VMCNT_S; }
            if (ph == 4) STAGE_A(tc2, 0, 0);
            if (ph == 5) STAGE_A(tc2, 0, 1);
            if (ph == 6) STAGE_B(tc3, 1, 0);
            if (ph == 7) { STAGE_B(tc3, 1, 1); VMCNT_S; }

            __builtin_amdgcn_s_barrier();
            __builtin_amdgcn_s_setprio(1);
            #pragma unroll
            for (int i = 0; i < 2; ++i)
                #pragma unroll
                for (int n = 0; n < NB; ++n) {
                    acc[2 * q + i][n] = __builtin_amdgcn_mfma_f32_16x16x32_bf16(
                        af[i][0], bfrag[n][0], acc[2 * q + i][n], 0, 0, 0);
                    acc[2 * q + i][n] = __builtin_amdgcn_mfma_f32_16x16x32_bf16(
                        af[i][1], bfrag[n][1], acc[2 * q + i][n], 0, 0, 0);
                }
            __builtin_amdgcn_s_setprio(0);
            __builtin_amdgcn_s_barrier();
        }
    }

    // epilogue: C/D layout col = lane&15, row = (lane>>4)*4 + rr (m89-verified)
    #pragma unroll
    for (int m = 0; m < 8; ++m) {
        #pragma unroll
        for (int n = 0; n < NB; ++n) {
            const int ccol = bcol + wn * (BN / 4) + n * 16 + fr;
            #pragma unroll
            for (int rr = 0; rr < 4; ++rr) {
                const long crow = brow + wr * 128 + m * 16 + g * 4 + rr;
                const float v = acc[m][n][rr] * alpha;
                if constexpr (OUT == 0) {
                    ((float*)Cp + bz * sC)[crow * ldc + ccol] = v;
                } else {
                    ((bf16*)Cp + bz * sC)[crow * ldc + ccol] = (bf16)v;
                }
            }
        }
    }
}

// fp32 -> bf16 cast, vectorized x4, grid-stride.
__global__ __launch_bounds__(256)
void cast_bf16(const float* __restrict__ in, bf16* __restrict__ out, int n4)
{
    int i = blockIdx.x * 256 + threadIdx.x;
    const int stride = gridDim.x * 256;
    for (; i < n4; i += stride) {
        float4 v = reinterpret_cast<const float4*>(in)[i];
        bf16x4 o = { (bf16)v.x, (bf16)v.y, (bf16)v.z, (bf16)v.w };
        reinterpret_cast<bf16x4*>(out)[i] = o;
    }
}

// fused Wq|Wk|Wv cast into contiguous [3072,1024] bf16 dst (Wqk then Wv).
__global__ __launch_bounds__(256)
void cast_w3(const float* __restrict__ Wq, const float* __restrict__ Wk,
             const float* __restrict__ Wv, bf16* __restrict__ dst)
{
    const int idx = blockIdx.x * 256 + threadIdx.x;     // 0 .. 786431
    const float* src;
    int off;
    if (idx < 262144)      { src = Wq; off = idx; }
    else if (idx < 524288) { src = Wk; off = idx - 262144; }
    else                   { src = Wv; off = idx - 524288; }
    float4 v = reinterpret_cast<const float4*>(src)[off];
    bf16x4 o = { (bf16)v.x, (bf16)v.y, (bf16)v.z, (bf16)v.w };
    reinterpret_cast<bf16x4*>(dst)[idx] = o;
}

// In-place row softmax (f32) + bf16 copy; one block per row of 2048.
__global__ __launch_bounds__(256)
void softmax_rows(float* __restrict__ W, bf16* __restrict__ Wb)
{
    float* p  = W  + (long)blockIdx.x * 2048;
    bf16*  pb = Wb + (long)blockIdx.x * 2048;
    const int tid  = threadIdx.x;
    const int wid  = tid >> 6;
    const int lane = tid & 63;

    float4 v0 = reinterpret_cast<const float4*>(p)[tid];
    float4 v1 = reinterpret_cast<const float4*>(p)[tid + 256];

    float m = fmaxf(fmaxf(fmaxf(v0.x, v0.y), fmaxf(v0.z, v0.w)),
                    fmaxf(fmaxf(v1.x, v1.y), fmaxf(v1.z, v1.w)));
    #pragma unroll
    for (int off = 32; off >= 1; off >>= 1)
        m = fmaxf(m, __shfl_xor(m, off));

    __shared__ float red[8];
    if (lane == 0) red[wid] = m;
    __syncthreads();
    m = fmaxf(fmaxf(red[0], red[1]), fmaxf(red[2], red[3]));

    v0.x = __expf(v0.x - m); v0.y = __expf(v0.y - m);
    v0.z = __expf(v0.z - m); v0.w = __expf(v0.w - m);
    v1.x = __expf(v1.x - m); v1.y = __expf(v1.y - m);
    v1.z = __expf(v1.z - m); v1.w = __expf(v1.w - m);

    float s = (v0.x + v0.y + v0.z + v0.w) + (v1.x + v1.y + v1.z + v1.w);
    #pragma unroll
    for (int off = 32; off >= 1; off >>= 1)
        s += __shfl_xor(s, off);
    __syncthreads();
    if (lane == 0) red[4 + wid] = s;
    __syncthreads();
    s = (red[4] + red[5]) + (red[6] + red[7]);

    const float inv = 1.f / s;
    v0.x *= inv; v0.y *= inv; v0.z *= inv; v0.w *= inv;
    v1.x *= inv; v1.y *= inv; v1.z *= inv; v1.w *= inv;
    reinterpret_cast<float4*>(p)[tid]       = v0;
    reinterpret_cast<float4*>(p)[tid + 256] = v1;
    bf16x4 b0 = { (bf16)v0.x, (bf16)v0.y, (bf16)v0.z, (bf16)v0.w };
    bf16x4 b1 = { (bf16)v1.x, (bf16)v1.y, (bf16)v1.z, (bf16)v1.w };
    reinterpret_cast<bf16x4*>(pb)[tid]       = b0;
    reinterpret_cast<bf16x4*>(pb)[tid + 256] = b1;
}

extern "C" void kernel_launch(void* const* d_in, const int* in_sizes, int n_in,
                              void* d_out, int out_size, void* d_ws, size_t ws_size,
                              hipStream_t stream)
{
    const float* X  = (const float*)d_in[0];   // [4,2048,1024]
    const float* Wq = (const float*)d_in[1];   // [1024,1024]
    const float* Wk = (const float*)d_in[2];
    const float* Wv = (const float*)d_in[3];

    const long BT = 4L * 2048;                 // 8192 total rows
    const long D  = 1024;
    const long S  = 2048;
    const long MiB = 1024 * 1024;

    float* ctx = (float*)d_out;                // [4,2048,1024]
    float* wts = (float*)d_out + BT * D;       // [4,2048,2048]

    char* ws   = (char*)d_ws;
    bf16* Xb   = (bf16*)(ws);                  // 16 MiB [0,16)
    bf16* Wqkb = (bf16*)(ws + 16 * MiB);       //  4 MiB [16,20)  [2048,1024]
    bf16* Wvb  = (bf16*)(ws + 20 * MiB);       //  2 MiB (contig after Wqkb)
    bf16* QKb  = (bf16*)(ws + 22 * MiB);       // 32 MiB [22,54)  [8192,2048]
    bf16* Vtb  = (bf16*)(ws + 54 * MiB);       // 16 MiB [54,70)  [1024,8192]
    bf16* Wbf  = (bf16*)(ws);                  // 32 MiB, aliases dead [0,32)

    dim3 blk(256), blk8(512);

    // casts: X -> Xb ; Wq|Wk|Wv -> [Wqkb|Wvb] contiguous
    cast_bf16<<<dim3(2048), blk, 0, stream>>>(X, Xb, (int)(BT * D / 4));
    cast_w3<<<dim3(3072), blk, 0, stream>>>(Wq, Wk, Wv, Wqkb);

    // fused QK projection: QKb[8192,2048] = NT(Xb, Wqkb)   (256 blocks)
    gemm8<1, 256><<<dim3(8, 32, 1), blk8, 0, stream>>>(
        Xb, Wqkb, QKb, 16, 1024, 1024, 2048, 0, 0, 0, 1.f);
    // Vt projection: Vtb[1024,8192] = NT(Wvb, Xb)   BN=128 -> 256 blocks
    gemm8<1, 128><<<dim3(64, 4, 1), blk8, 0, stream>>>(
        Wvb, Xb, Vtb, 16, 1024, 1024, 8192, 0, 0, 0, 1.f);
    // scores: S_b = NT(Q_b, K_b) / 32 -> f32 weights region   (256 blocks)
    gemm8<0, 256><<<dim3(8, 8, 4), blk8, 0, stream>>>(
        QKb, QKb + 1024, wts, 16, 2048, 2048, 2048,
        S * 2048, S * 2048, S * S, 0.03125f);
    // softmax rows (f32 in place) + bf16 copy
    softmax_rows<<<dim3(BT), blk, 0, stream>>>(wts, Wbf);

    // context: ctx_b = NT(Wbf_b, Vt[:, b*2048..])  BN=128 -> 256 blocks, K=2048
    gemm8<0, 128><<<dim3(8, 8, 4), blk8, 0, stream>>>(
        Wbf, Vtb, ctx, 32, 2048, 8192, 1024,
        S * S, S, S * D, 1.f);
}